// Round 7
// baseline (49.833 us; speedup 1.0000x reference)
//
#include <hip/hip_runtime.h>
#include <hip/hip_bf16.h>
#include <math.h>

#define EPSF 1e-8f

constexpr int N_OBJ  = 8192;
constexpr int M_SR   = 4096;
constexpr int N_FACE = 2048;

// ---------------- ws layout (every byte overwritten each call; no init) ----------------
// fd    : float  [N_FACE][16]  face constants                     128 KB
// cand  : float2 [32][N_OBJ]   per-split NN candidates (m, idx)     2 MB
// pend2 : float  [N_OBJ]       best d2 per point                   32 KB
// gcnt8 : u8     [32][N_OBJ]   per-face-split hit counts          256 KB
constexpr size_t OFF_CAND = 128 * 1024;
constexpr size_t OFF_PEN  = OFF_CAND + 32ull * N_OBJ * sizeof(float2);
constexpr size_t OFF_GC   = OFF_PEN + N_OBJ * sizeof(float);

// ================= K1: NN partials (point-per-lane, scalar sr loads) + face setup =================
constexpr int NN_SPLITS   = 32;
constexpr int SR_PER_SPL  = M_SR / NN_SPLITS;    // 128
constexpr int NN_PTBLK    = N_OBJ / 256;         // 32
constexpr int NN_BLOCKS   = NN_PTBLK * NN_SPLITS;// 1024
constexpr int SETUP_BLKS  = N_FACE / 256;        // 8

__global__ __launch_bounds__(256) void k1_nn_setup(
    const float* __restrict__ obj, const float* __restrict__ srp,
    const float* __restrict__ verts, const int* __restrict__ faces,
    const float* __restrict__ fnorm, float* __restrict__ fd,
    float2* __restrict__ cand)
{
    const int b   = blockIdx.x;
    const int tid = threadIdx.x;

    if (b >= NN_BLOCKS) {
        // ---- face constant setup ----
        int f = (b - NN_BLOCKS) * 256 + tid;
        int i0 = faces[3 * f + 0], i1 = faces[3 * f + 1], i2 = faces[3 * f + 2];
        float ax = verts[3 * i0 + 0], ay = verts[3 * i0 + 1], az = verts[3 * i0 + 2];
        float bx = verts[3 * i1 + 0], by = verts[3 * i1 + 1], bz = verts[3 * i1 + 2];
        float cx = verts[3 * i2 + 0], cy = verts[3 * i2 + 1], cz = verts[3 * i2 + 2];
        float fx = fnorm[3 * f + 0], fy = fnorm[3 * f + 1], fz = fnorm[3 * f + 2];
        float nf = fx * ax + fy * ay + fz * az;

        float e0x = bx - ax, e0y = by - ay, e0z = bz - az;
        float g0x = fy * e0z - fz * e0y, g0y = fz * e0x - fx * e0z, g0z = fx * e0y - fy * e0x;
        float h0  = g0x * ax + g0y * ay + g0z * az;
        float e1x = cx - bx, e1y = cy - by, e1z = cz - bz;
        float g1x = fy * e1z - fz * e1y, g1y = fz * e1x - fx * e1z, g1z = fx * e1y - fy * e1x;
        float h1  = g1x * bx + g1y * by + g1z * bz;
        float e2x = ax - cx, e2y = ay - cy, e2z = az - cz;
        float g2x = fy * e2z - fz * e2y, g2y = fz * e2x - fx * e2z, g2z = fx * e2y - fy * e2x;
        float h2  = g2x * cx + g2y * cy + g2z * cz;

        float* o = fd + f * 16;
        o[0] = fx;  o[1] = fy;  o[2] = fz;  o[3] = nf;
        o[4] = g0x; o[5] = g0y; o[6] = g0z; o[7] = h0;
        o[8] = g1x; o[9] = g1y; o[10] = g1z; o[11] = h1;
        o[12] = g2x; o[13] = g2y; o[14] = g2z; o[15] = h2;
        return;
    }

    // ---- NN partial: this block = 256 points x one sr split of 128 ----
    const int sp    = b & (NN_SPLITS - 1);
    const int ptblk = b / NN_SPLITS;
    const int p     = ptblk * 256 + tid;

    const float ox = obj[3 * p], oy = obj[3 * p + 1], oz = obj[3 * p + 2];
    const float* __restrict__ s = srp + 3 * sp * SR_PER_SPL;

    float best = 3.4e38f;
    int   bi   = 0;
#pragma unroll 8
    for (int j = 0; j < SR_PER_SPL; ++j) {
        // wave-uniform addresses -> scalar loads
        float dx = ox - s[3 * j + 0];
        float dy = oy - s[3 * j + 1];
        float dz = oz - s[3 * j + 2];
        float d2 = dx * dx + dy * dy + dz * dz;
        if (d2 < best) { best = d2; bi = sp * SR_PER_SPL + j; }
    }
    cand[sp * N_OBJ + p] = make_float2(best, __int_as_float(bi));
}

// ================= K2: ray-triangle parity (point-per-lane, SGPR face consts) =================
constexpr int FK_SPLITS = 32;                 // 64 faces each
constexpr int FK_PTBLK  = N_OBJ / 256;        // 32
constexpr int FK_NBLK   = FK_PTBLK * FK_SPLITS; // 1024

__global__ __launch_bounds__(256) void k2_face(
    const float* __restrict__ obj, const float* __restrict__ srp,
    const float* __restrict__ fd, const float2* __restrict__ cand,
    float* __restrict__ out, float* __restrict__ pend2,
    unsigned char* __restrict__ gcnt8)
{
    const int tid   = threadIdx.x;
    const int fs    = blockIdx.x & (FK_SPLITS - 1);
    const int ptblk = blockIdx.x / FK_SPLITS;
    const int p     = ptblk * 256 + tid;

    // ---- merge NN candidates (ordered -> first-min tie-break) ----
    float best = 3.4e38f;
    int   bi   = 0;
#pragma unroll
    for (int s = 0; s < NN_SPLITS; ++s) {
        float2 c = cand[s * N_OBJ + p];
        if (c.x < best) { best = c.x; bi = __float_as_int(c.y); }
    }

    const float ox = obj[3 * p], oy = obj[3 * p + 1], oz = obj[3 * p + 2];
    const float pdx = srp[3 * bi + 0] - ox;
    const float pdy = srp[3 * bi + 1] - oy;
    const float pdz = srp[3 * bi + 2] - oz;

    if (fs == 0) {
        pend2[p] = best;
        out[1 + p] = 2.0f / (1.0f + expf(100.0f * sqrtf(best + EPSF)));
    }

    const float* __restrict__ c = fd + (fs * 64) * 16;
    int cnt = 0;
#pragma unroll 4
    for (int j = 0; j < 64; ++j) {
        const float fx  = c[16 * j + 0],  fy  = c[16 * j + 1];
        const float fz  = c[16 * j + 2],  nf  = c[16 * j + 3];
        const float g0x = c[16 * j + 4],  g0y = c[16 * j + 5];
        const float g0z = c[16 * j + 6],  h0  = c[16 * j + 7];
        const float g1x = c[16 * j + 8],  g1y = c[16 * j + 9];
        const float g1z = c[16 * j + 10], h1  = c[16 * j + 11];
        const float g2x = c[16 * j + 12], g2y = c[16 * j + 13];
        const float g2z = c[16 * j + 14], h2  = c[16 * j + 15];

        float den = fx * pdx + fy * pdy + fz * pdz;
        float num = nf - (fx * ox + fy * oy + fz * oz);
        float Px  = den * ox + num * pdx;
        float Py  = den * oy + num * pdy;
        float Pz  = den * oz + num * pdz;
        bool pos = den >= 0.0f;
        bool ok0 = ((g0x * Px + g0y * Py + g0z * Pz - den * h0) >= 0.0f) == pos;
        bool ok1 = ((g1x * Px + g1y * Py + g1z * Pz - den * h1) >= 0.0f) == pos;
        bool ok2 = ((g2x * Px + g2y * Py + g2z * Pz - den * h2) >= 0.0f) == pos;
        bool tok = (num >= 0.0f) == pos;
        bool aok = fabsf(den) >= EPSF;
        cnt += (ok0 & ok1 & ok2 & tok & aok) ? 1 : 0;
    }
    gcnt8[fs * N_OBJ + p] = (unsigned char)cnt;   // fully overwritten every call
}

// ================= K3: packed-XOR parity -> pen_dist =================
__global__ __launch_bounds__(1024) void k3_fin(
    const float* __restrict__ pend2, const unsigned char* __restrict__ gcnt8,
    float* __restrict__ out)
{
    __shared__ float wsum[16];
    const int t  = threadIdx.x;
    const int p0 = t * 8;

    unsigned int xlo = 0, xhi = 0;
#pragma unroll
    for (int fs = 0; fs < FK_SPLITS; ++fs) {
        uint2 v = *(const uint2*)(gcnt8 + fs * N_OBJ + p0);
        xlo ^= v.x; xhi ^= v.y;   // parity(sum) == xor of parities per byte lane
    }
    float4 a = *(const float4*)(pend2 + p0);
    float4 b = *(const float4*)(pend2 + p0 + 4);
    float s = 0.0f;
    if (xlo & 0x1u)        s += a.x;
    if (xlo & 0x100u)      s += a.y;
    if (xlo & 0x10000u)    s += a.z;
    if (xlo & 0x1000000u)  s += a.w;
    if (xhi & 0x1u)        s += b.x;
    if (xhi & 0x100u)      s += b.y;
    if (xhi & 0x10000u)    s += b.z;
    if (xhi & 0x1000000u)  s += b.w;

    for (int off = 1; off < 64; off <<= 1) s += __shfl_xor(s, off);
    if ((t & 63) == 0) wsum[t >> 6] = s;
    __syncthreads();
    if (t == 0) {
        float tot = 0.0f;
#pragma unroll
        for (int k = 0; k < 16; ++k) tot += wsum[k];
        out[0] = sqrtf(tot);
    }
}

extern "C" void kernel_launch(void* const* d_in, const int* in_sizes, int n_in,
                              void* d_out, int out_size, void* d_ws, size_t ws_size,
                              hipStream_t stream)
{
    const float* obj   = (const float*)d_in[0];
    const float* srp   = (const float*)d_in[1];
    const float* verts = (const float*)d_in[2];
    const int*   faces = (const int*)d_in[3];
    const float* fnorm = (const float*)d_in[4];
    float*       out   = (float*)d_out;

    float*         fd    = (float*)d_ws;
    float2*        cand  = (float2*)((char*)d_ws + OFF_CAND);
    float*         pend2 = (float*)((char*)d_ws + OFF_PEN);
    unsigned char* gcnt8 = (unsigned char*)((char*)d_ws + OFF_GC);

    k1_nn_setup<<<NN_BLOCKS + SETUP_BLKS, 256, 0, stream>>>(obj, srp, verts, faces, fnorm, fd, cand);
    k2_face<<<FK_NBLK, 256, 0, stream>>>(obj, srp, fd, cand, out, pend2, gcnt8);
    k3_fin<<<1, 1024, 0, stream>>>(pend2, gcnt8, out);
}

// Round 8
// 38.286 us; speedup vs baseline: 1.3016x; 1.3016x over previous
//
#include <hip/hip_runtime.h>
#include <hip/hip_bf16.h>
#include <math.h>

#define EPSF 1e-8f

constexpr int N_OBJ  = 8192;
constexpr int M_SR   = 4096;
constexpr int N_FACE = 2048;

// ---------------- ws layout (every byte overwritten each call; no init) ----------------
// ptrec : float4 [2*N_OBJ]   rec[2p]=(ox,oy,oz,d2), rec[2p+1]=(dx,dy,dz,0)   256 KB
// fd    : float  [N_FACE][16] face constants (4 x float4 per face)           128 KB
// pend2 : float  [N_OBJ]      best d2 per point                               32 KB
// bm    : u64    [64][128]    per-face-split parity bitmasks                  64 KB
constexpr size_t OFF_FD  = 2ull * N_OBJ * sizeof(float4);
constexpr size_t OFF_PEN = OFF_FD + (size_t)N_FACE * 16 * sizeof(float);
constexpr size_t OFF_BM  = OFF_PEN + (size_t)N_OBJ * sizeof(float);

// ================= D1: NN (LDS-tiled, 4 pts/wave) + face constant setup =================
constexpr int SRTILE  = 2048;
constexpr int NN_PPW  = 4;
constexpr int NN_PPB  = NN_PPW * 4;           // 16
constexpr int NN_NBLK = N_OBJ / NN_PPB;       // 512
constexpr int SETUP_BLKS = N_FACE / 256;      // 8

__global__ __launch_bounds__(256, 4) void d1_nn_setup(
    const float* __restrict__ obj, const float* __restrict__ srp,
    const float* __restrict__ verts, const int* __restrict__ faces,
    const float* __restrict__ fnorm, float* __restrict__ fd,
    float* __restrict__ out, float4* __restrict__ ptrec,
    float* __restrict__ pend2)
{
    const int b   = blockIdx.x;
    const int tid = threadIdx.x;

    if (b >= NN_NBLK) {
        // ---- face constant setup ----
        int f = (b - NN_NBLK) * 256 + tid;
        int i0 = faces[3 * f + 0], i1 = faces[3 * f + 1], i2 = faces[3 * f + 2];
        float ax = verts[3 * i0 + 0], ay = verts[3 * i0 + 1], az = verts[3 * i0 + 2];
        float bx = verts[3 * i1 + 0], by = verts[3 * i1 + 1], bz = verts[3 * i1 + 2];
        float cx = verts[3 * i2 + 0], cy = verts[3 * i2 + 1], cz = verts[3 * i2 + 2];
        float fx = fnorm[3 * f + 0], fy = fnorm[3 * f + 1], fz = fnorm[3 * f + 2];
        float nf = fx * ax + fy * ay + fz * az;

        float e0x = bx - ax, e0y = by - ay, e0z = bz - az;
        float g0x = fy * e0z - fz * e0y, g0y = fz * e0x - fx * e0z, g0z = fx * e0y - fy * e0x;
        float h0  = g0x * ax + g0y * ay + g0z * az;
        float e1x = cx - bx, e1y = cy - by, e1z = cz - bz;
        float g1x = fy * e1z - fz * e1y, g1y = fz * e1x - fx * e1z, g1z = fx * e1y - fy * e1x;
        float h1  = g1x * bx + g1y * by + g1z * bz;
        float e2x = ax - cx, e2y = ay - cy, e2z = az - cz;
        float g2x = fy * e2z - fz * e2y, g2y = fz * e2x - fx * e2z, g2z = fx * e2y - fy * e2x;
        float h2  = g2x * cx + g2y * cy + g2z * cz;

        float* o = fd + f * 16;
        o[0] = fx;  o[1] = fy;  o[2] = fz;  o[3] = nf;
        o[4] = g0x; o[5] = g0y; o[6] = g0z; o[7] = h0;
        o[8] = g1x; o[9] = g1y; o[10] = g1z; o[11] = h1;
        o[12] = g2x; o[13] = g2y; o[14] = g2z; o[15] = h2;
        return;
    }

    __shared__ float4 s4[SRTILE];
    const int w    = tid >> 6;
    const int lane = tid & 63;
    const int pbase = b * NN_PPB + w * NN_PPW;

    float ox[NN_PPW], oy[NN_PPW], oz[NN_PPW], oo[NN_PPW], best[NN_PPW];
    int bi[NN_PPW];
#pragma unroll
    for (int q = 0; q < NN_PPW; ++q) {
        int n = pbase + q;
        ox[q] = obj[3 * n]; oy[q] = obj[3 * n + 1]; oz[q] = obj[3 * n + 2];
        oo[q] = ox[q] * ox[q] + oy[q] * oy[q] + oz[q] * oz[q];
        best[q] = 3.4e38f; bi[q] = 0;
    }

    for (int t0 = 0; t0 < M_SR; t0 += SRTILE) {
        __syncthreads();
        for (int i = tid; i < SRTILE; i += 256) {
            float sx = srp[3 * (t0 + i) + 0];
            float sy = srp[3 * (t0 + i) + 1];
            float sz = srp[3 * (t0 + i) + 2];
            s4[i] = make_float4(sx, sy, sz, sx * sx + sy * sy + sz * sz);
        }
        __syncthreads();
#pragma unroll 2
        for (int j = 0; j < SRTILE / 64; ++j) {
            int s = j * 64 + lane;
            float4 v = s4[s];
#pragma unroll
            for (int q = 0; q < NN_PPW; ++q) {
                float m = v.w - 2.0f * (ox[q] * v.x + oy[q] * v.y + oz[q] * v.z);
                if (m < best[q]) { best[q] = m; bi[q] = t0 + s; }
            }
        }
    }
    for (int off = 1; off < 64; off <<= 1) {
#pragma unroll
        for (int q = 0; q < NN_PPW; ++q) {
            float od = __shfl_xor(best[q], off);
            int   oi = __shfl_xor(bi[q], off);
            if (od < best[q] || (od == best[q] && oi < bi[q])) { best[q] = od; bi[q] = oi; }
        }
    }
    if (lane == 0) {
#pragma unroll
        for (int q = 0; q < NN_PPW; ++q) {
            int n = pbase + q;
            float d2 = best[q] + oo[q];
            float dx = srp[3 * bi[q]] - ox[q];
            float dy = srp[3 * bi[q] + 1] - oy[q];
            float dz = srp[3 * bi[q] + 2] - oz[q];
            ptrec[2 * n]     = make_float4(ox[q], oy[q], oz[q], d2);
            ptrec[2 * n + 1] = make_float4(dx, dy, dz, 0.0f);
            pend2[n] = d2;
            out[1 + n] = 2.0f / (1.0f + expf(100.0f * sqrtf(d2 + EPSF)));
        }
    }
}

// ====== D2: face parity (point-per-lane, float4 const broadcast, ballot bits) ======
constexpr int FK_SPLITS = 64;                    // 32 faces each
constexpr int FK_PTBLK  = N_OBJ / 256;           // 32
constexpr int FK_NBLK   = FK_PTBLK * FK_SPLITS;  // 2048

__global__ __launch_bounds__(256, 8) void d2_face(
    const float* __restrict__ fd, const float4* __restrict__ ptrec,
    unsigned long long* __restrict__ bm)
{
    const int tid   = threadIdx.x;
    const int w     = tid >> 6;
    const int lane  = tid & 63;
    const int fs    = blockIdx.x & (FK_SPLITS - 1);
    const int ptblk = blockIdx.x >> 6;
    const int p     = ptblk * 256 + tid;

    float4 r0 = ptrec[2 * p];
    float4 r1 = ptrec[2 * p + 1];
    const float ox = r0.x, oy = r0.y, oz = r0.z;
    const float dx = r1.x, dy = r1.y, dz = r1.z;

    const float4* __restrict__ c4 = (const float4*)fd + (size_t)(fs * 32) * 4;

    int cnt = 0;
#pragma unroll 4
    for (int j = 0; j < 32; ++j) {
        float4 q0 = c4[4 * j + 0];
        float den = q0.x * dx + q0.y * dy + q0.z * dz;
        float num = q0.w - (q0.x * ox + q0.y * oy + q0.z * oz);
        float Px  = den * ox + num * dx;
        float Py  = den * oy + num * dy;
        float Pz  = den * oz + num * dz;
        bool pos = den >= 0.0f;

        float4 q1 = c4[4 * j + 1];
        bool ok0 = ((q1.x * Px + q1.y * Py + q1.z * Pz - den * q1.w) >= 0.0f) == pos;
        float4 q2 = c4[4 * j + 2];
        bool ok1 = ((q2.x * Px + q2.y * Py + q2.z * Pz - den * q2.w) >= 0.0f) == pos;
        float4 q3 = c4[4 * j + 3];
        bool ok2 = ((q3.x * Px + q3.y * Py + q3.z * Pz - den * q3.w) >= 0.0f) == pos;

        bool tok = (num >= 0.0f) == pos;
        bool aok = fabsf(den) >= EPSF;
        cnt += (ok0 & ok1 & ok2 & tok & aok) ? 1 : 0;
    }

    unsigned long long m = __ballot((cnt & 1) != 0);
    if (lane == 0) bm[(size_t)fs * 128 + ptblk * 4 + w] = m;
}

// ================= D3: XOR parity masks -> pen_dist =================
__global__ __launch_bounds__(256) void d3_fin(
    const float* __restrict__ pend2, const unsigned long long* __restrict__ bm,
    float* __restrict__ out)
{
    __shared__ float wsum[4];
    const int t = threadIdx.x;
    float s = 0.0f;
    if (t < 128) {
        unsigned long long x = 0;
#pragma unroll
        for (int fs = 0; fs < FK_SPLITS; ++fs) x ^= bm[(size_t)fs * 128 + t];
        const float4* p4 = (const float4*)(pend2 + t * 64);
#pragma unroll
        for (int k = 0; k < 16; ++k) {
            float4 v = p4[k];
            unsigned int nib = (unsigned int)(x >> (4 * k)) & 0xFu;
            s += (nib & 1u) ? v.x : 0.0f;
            s += (nib & 2u) ? v.y : 0.0f;
            s += (nib & 4u) ? v.z : 0.0f;
            s += (nib & 8u) ? v.w : 0.0f;
        }
    }
    for (int off = 1; off < 64; off <<= 1) s += __shfl_xor(s, off);
    if ((t & 63) == 0) wsum[t >> 6] = s;
    __syncthreads();
    if (t == 0) out[0] = sqrtf(wsum[0] + wsum[1] + wsum[2] + wsum[3]);
}

extern "C" void kernel_launch(void* const* d_in, const int* in_sizes, int n_in,
                              void* d_out, int out_size, void* d_ws, size_t ws_size,
                              hipStream_t stream)
{
    const float* obj   = (const float*)d_in[0];
    const float* srp   = (const float*)d_in[1];
    const float* verts = (const float*)d_in[2];
    const int*   faces = (const int*)d_in[3];
    const float* fnorm = (const float*)d_in[4];
    float*       out   = (float*)d_out;

    float4*             ptrec = (float4*)d_ws;
    float*              fd    = (float*)((char*)d_ws + OFF_FD);
    float*              pend2 = (float*)((char*)d_ws + OFF_PEN);
    unsigned long long* bm    = (unsigned long long*)((char*)d_ws + OFF_BM);

    d1_nn_setup<<<NN_NBLK + SETUP_BLKS, 256, 0, stream>>>(obj, srp, verts, faces, fnorm,
                                                          fd, out, ptrec, pend2);
    d2_face<<<FK_NBLK, 256, 0, stream>>>(fd, ptrec, bm);
    d3_fin<<<1, 256, 0, stream>>>(pend2, bm, out);
}

// Round 9
// 37.131 us; speedup vs baseline: 1.3421x; 1.0311x over previous
//
#include <hip/hip_runtime.h>
#include <hip/hip_bf16.h>
#include <math.h>

#define EPSF 1e-8f

constexpr int N_OBJ  = 8192;
constexpr int M_SR   = 4096;
constexpr int N_FACE = 2048;

// ---------------- ws layout (every byte overwritten each call; no init) ----------------
// fd    : float  [N_FACE][16]   face constants (4 x float4 per face)     128 KB
// cand  : float4 [2][N_OBJ]     per-sr-half NN candidate (dx,dy,dz,m)    256 KB
// pend2 : float  [N_OBJ]        best d2 per point                         32 KB
// bm    : u64    [128][64]      parity bitmasks, [pt-column][face-split]  64 KB
constexpr size_t OFF_CAND = (size_t)N_FACE * 16 * sizeof(float);
constexpr size_t OFF_PEN  = OFF_CAND + 2ull * N_OBJ * sizeof(float4);
constexpr size_t OFF_BM   = OFF_PEN + (size_t)N_OBJ * sizeof(float);

// ================= D1: NN over one sr-half (LDS-tiled) + face constant setup =================
constexpr int SR_HALF = M_SR / 2;            // 2048
constexpr int SRTILE  = 1024;                // 16 KB LDS
constexpr int NN_PPW  = 4;
constexpr int NN_PPB  = NN_PPW * 4;          // 16 points per block
constexpr int NN_NBLK = (N_OBJ / NN_PPB) * 2; // 1024 (x2 sr halves)
constexpr int SETUP_BLKS = N_FACE / 256;     // 8

__global__ __launch_bounds__(256) void d1_nn_setup(
    const float* __restrict__ obj, const float* __restrict__ srp,
    const float* __restrict__ verts, const int* __restrict__ faces,
    const float* __restrict__ fnorm, float* __restrict__ fd,
    float4* __restrict__ cand)
{
    const int b   = blockIdx.x;
    const int tid = threadIdx.x;

    if (b >= NN_NBLK) {
        // ---- face constant setup ----
        int f = (b - NN_NBLK) * 256 + tid;
        int i0 = faces[3 * f + 0], i1 = faces[3 * f + 1], i2 = faces[3 * f + 2];
        float ax = verts[3 * i0 + 0], ay = verts[3 * i0 + 1], az = verts[3 * i0 + 2];
        float bx = verts[3 * i1 + 0], by = verts[3 * i1 + 1], bz = verts[3 * i1 + 2];
        float cx = verts[3 * i2 + 0], cy = verts[3 * i2 + 1], cz = verts[3 * i2 + 2];
        float fx = fnorm[3 * f + 0], fy = fnorm[3 * f + 1], fz = fnorm[3 * f + 2];
        float nf = fx * ax + fy * ay + fz * az;

        float e0x = bx - ax, e0y = by - ay, e0z = bz - az;
        float g0x = fy * e0z - fz * e0y, g0y = fz * e0x - fx * e0z, g0z = fx * e0y - fy * e0x;
        float h0  = g0x * ax + g0y * ay + g0z * az;
        float e1x = cx - bx, e1y = cy - by, e1z = cz - bz;
        float g1x = fy * e1z - fz * e1y, g1y = fz * e1x - fx * e1z, g1z = fx * e1y - fy * e1x;
        float h1  = g1x * bx + g1y * by + g1z * bz;
        float e2x = ax - cx, e2y = ay - cy, e2z = az - cz;
        float g2x = fy * e2z - fz * e2y, g2y = fz * e2x - fx * e2z, g2z = fx * e2y - fy * e2x;
        float h2  = g2x * cx + g2y * cy + g2z * cz;

        float* o = fd + f * 16;
        o[0] = fx;  o[1] = fy;  o[2] = fz;  o[3] = nf;
        o[4] = g0x; o[5] = g0y; o[6] = g0z; o[7] = h0;
        o[8] = g1x; o[9] = g1y; o[10] = g1z; o[11] = h1;
        o[12] = g2x; o[13] = g2y; o[14] = g2z; o[15] = h2;
        return;
    }

    // ---- NN: this block = 16 points x one sr half ----
    __shared__ float4 s4[SRTILE];
    const int half = b & 1;
    const int ptg  = b >> 1;
    const int w    = tid >> 6;
    const int lane = tid & 63;
    const int pbase = ptg * NN_PPB + w * NN_PPW;
    const float* __restrict__ sbase = srp + 3 * half * SR_HALF;

    float ox[NN_PPW], oy[NN_PPW], oz[NN_PPW], best[NN_PPW];
    int bi[NN_PPW];
#pragma unroll
    for (int q = 0; q < NN_PPW; ++q) {
        int n = pbase + q;
        ox[q] = obj[3 * n]; oy[q] = obj[3 * n + 1]; oz[q] = obj[3 * n + 2];
        best[q] = 3.4e38f; bi[q] = 0;
    }

    for (int t0 = 0; t0 < SR_HALF; t0 += SRTILE) {
        __syncthreads();
        for (int i = tid; i < SRTILE; i += 256) {
            float sx = sbase[3 * (t0 + i) + 0];
            float sy = sbase[3 * (t0 + i) + 1];
            float sz = sbase[3 * (t0 + i) + 2];
            s4[i] = make_float4(sx, sy, sz, sx * sx + sy * sy + sz * sz);
        }
        __syncthreads();
#pragma unroll 4
        for (int j = 0; j < SRTILE / 64; ++j) {
            int s = j * 64 + lane;
            float4 v = s4[s];
#pragma unroll
            for (int q = 0; q < NN_PPW; ++q) {
                float m = v.w - 2.0f * (ox[q] * v.x + oy[q] * v.y + oz[q] * v.z);
                if (m < best[q]) { best[q] = m; bi[q] = t0 + s; }
            }
        }
    }
    for (int off = 1; off < 64; off <<= 1) {
#pragma unroll
        for (int q = 0; q < NN_PPW; ++q) {
            float od = __shfl_xor(best[q], off);
            int   oi = __shfl_xor(bi[q], off);
            if (od < best[q] || (od == best[q] && oi < bi[q])) { best[q] = od; bi[q] = oi; }
        }
    }
    if (lane == 0) {
#pragma unroll
        for (int q = 0; q < NN_PPW; ++q) {
            int n  = pbase + q;
            int gi = half * SR_HALF + bi[q];
            float dx = srp[3 * gi + 0] - ox[q];
            float dy = srp[3 * gi + 1] - oy[q];
            float dz = srp[3 * gi + 2] - oz[q];
            cand[half * N_OBJ + n] = make_float4(dx, dy, dz, best[q]);
        }
    }
}

// ====== D2: face parity (point-per-lane, 2-way cand merge, ballot bits) ======
constexpr int FK_SPLITS = 64;                    // 32 faces each
constexpr int FK_PTBLK  = N_OBJ / 256;           // 32
constexpr int FK_NBLK   = FK_PTBLK * FK_SPLITS;  // 2048

__global__ __launch_bounds__(256, 4) void d2_face(
    const float* __restrict__ obj, const float* __restrict__ fd,
    const float4* __restrict__ cand, float* __restrict__ out,
    float* __restrict__ pend2, unsigned long long* __restrict__ bm)
{
    const int tid   = threadIdx.x;
    const int w     = tid >> 6;
    const int lane  = tid & 63;
    const int fs    = blockIdx.x & (FK_SPLITS - 1);
    const int ptblk = blockIdx.x >> 6;
    const int p     = ptblk * 256 + tid;

    // merge the two sr-half candidates (strict-less keeps half 0 => first-min)
    float4 c0 = cand[p];
    float4 c1 = cand[N_OBJ + p];
    const bool tb = c1.w < c0.w;
    const float dx = tb ? c1.x : c0.x;
    const float dy = tb ? c1.y : c0.y;
    const float dz = tb ? c1.z : c0.z;
    const float m  = tb ? c1.w : c0.w;

    const float ox = obj[3 * p], oy = obj[3 * p + 1], oz = obj[3 * p + 2];

    if (fs == 0) {
        float d2 = m + (ox * ox + oy * oy + oz * oz);
        pend2[p] = d2;
        out[1 + p] = 2.0f / (1.0f + expf(100.0f * sqrtf(d2 + EPSF)));
    }

    const float4* __restrict__ c4 = (const float4*)fd + (size_t)(fs * 32) * 4;

    int cnt = 0;
#pragma unroll 4
    for (int j = 0; j < 32; ++j) {
        float4 q0 = c4[4 * j + 0];
        float den = q0.x * dx + q0.y * dy + q0.z * dz;
        float num = q0.w - (q0.x * ox + q0.y * oy + q0.z * oz);
        float Px  = den * ox + num * dx;
        float Py  = den * oy + num * dy;
        float Pz  = den * oz + num * dz;
        bool pos = den >= 0.0f;

        float4 q1 = c4[4 * j + 1];
        bool ok0 = ((q1.x * Px + q1.y * Py + q1.z * Pz - den * q1.w) >= 0.0f) == pos;
        float4 q2 = c4[4 * j + 2];
        bool ok1 = ((q2.x * Px + q2.y * Py + q2.z * Pz - den * q2.w) >= 0.0f) == pos;
        float4 q3 = c4[4 * j + 3];
        bool ok2 = ((q3.x * Px + q3.y * Py + q3.z * Pz - den * q3.w) >= 0.0f) == pos;

        bool tok = (num >= 0.0f) == pos;
        bool aok = fabsf(den) >= EPSF;
        cnt += (ok0 & ok1 & ok2 & tok & aok) ? 1 : 0;
    }

    unsigned long long msk = __ballot((cnt & 1) != 0);
    if (lane == 0) bm[(size_t)(ptblk * 4 + w) * 64 + fs] = msk;   // [col][fs]
}

// ================= D3: XOR parity columns -> pen_dist =================
__global__ __launch_bounds__(256) void d3_fin(
    const float* __restrict__ pend2, const unsigned long long* __restrict__ bm,
    float* __restrict__ out)
{
    __shared__ float wsum[4];
    const int t    = threadIdx.x;
    const int col  = t >> 1;       // 0..127
    const int half = t & 1;        // low/high 32 points of the column

    // XOR this thread's 32 fs-slices of the column (contiguous 256 B)
    const ulonglong2* __restrict__ q2 =
        (const ulonglong2*)(bm + (size_t)col * 64) + half * 16;
    unsigned long long x = 0;
#pragma unroll
    for (int k = 0; k < 16; ++k) { ulonglong2 v = q2[k]; x ^= v.x ^ v.y; }
    x ^= __shfl_xor(x, 1);         // both threads now hold the full column parity

    unsigned int bits = (unsigned int)(x >> (half * 32));
    const float4* __restrict__ p4 = (const float4*)(pend2 + (size_t)col * 64 + half * 32);
    float s = 0.0f;
#pragma unroll
    for (int k = 0; k < 8; ++k) {
        float4 v = p4[k];
        unsigned int nib = (bits >> (4 * k)) & 0xFu;
        s += (nib & 1u) ? v.x : 0.0f;
        s += (nib & 2u) ? v.y : 0.0f;
        s += (nib & 4u) ? v.z : 0.0f;
        s += (nib & 8u) ? v.w : 0.0f;
    }

    for (int off = 1; off < 64; off <<= 1) s += __shfl_xor(s, off);
    if ((t & 63) == 0) wsum[t >> 6] = s;
    __syncthreads();
    if (t == 0) out[0] = sqrtf(wsum[0] + wsum[1] + wsum[2] + wsum[3]);
}

extern "C" void kernel_launch(void* const* d_in, const int* in_sizes, int n_in,
                              void* d_out, int out_size, void* d_ws, size_t ws_size,
                              hipStream_t stream)
{
    const float* obj   = (const float*)d_in[0];
    const float* srp   = (const float*)d_in[1];
    const float* verts = (const float*)d_in[2];
    const int*   faces = (const int*)d_in[3];
    const float* fnorm = (const float*)d_in[4];
    float*       out   = (float*)d_out;

    float*              fd    = (float*)d_ws;
    float4*             cand  = (float4*)((char*)d_ws + OFF_CAND);
    float*              pend2 = (float*)((char*)d_ws + OFF_PEN);
    unsigned long long* bm    = (unsigned long long*)((char*)d_ws + OFF_BM);

    d1_nn_setup<<<NN_NBLK + SETUP_BLKS, 256, 0, stream>>>(obj, srp, verts, faces, fnorm, fd, cand);
    d2_face<<<FK_NBLK, 256, 0, stream>>>(obj, fd, cand, out, pend2, bm);
    d3_fin<<<1, 256, 0, stream>>>(pend2, bm, out);
}